// Round 20
// baseline (114.326 us; speedup 1.0000x reference)
//
#include <hip/hip_runtime.h>
#include <math.h>

#define BB 512       // batch rows (M)
#define DD 512       // depth (K)
#define CC 100000    // classes (N)
#define MARGIN2 0.5f
#define PI_F 3.14159265358979323846f

#define BM 256
#define BN 128
#define BK 64
#define KSTEPS (DD / BK)     // 8
#define NPAN 782             // ceil(100000/128), last panel 32 cols
#define GRID (2 * NPAN)      // 1564 = 8*195 + 4

typedef __bf16 bf16x8 __attribute__((ext_vector_type(8)));
typedef float f32x4 __attribute__((ext_vector_type(4)));

static __device__ __forceinline__ unsigned short f2bf(float f) {
    union { float f; unsigned u; } v; v.f = f;
    unsigned r = v.u + 0x7FFFu + ((v.u >> 16) & 1u);   // round-to-nearest-even
    return (unsigned short)(r >> 16);
}

// swizzled LDS byte offset for row-major [row][64 x bf16] tiles (row stride 128B)
static __device__ __forceinline__ int swz(int row, int kbyte) {
    return row * 128 + (kbyte ^ ((row & 7) << 4));
}

// async global->LDS, 16B per lane; LDS dest = wave-uniform base + lane*16 (HW rule)
static __device__ __forceinline__ void gll16(const unsigned char* g, unsigned char* l) {
    __builtin_amdgcn_global_load_lds(
        (const __attribute__((address_space(1))) void*)g,
        (__attribute__((address_space(3))) void*)l, 16, 0, 0);
}

// ---------------- K1: row-normalize x -> bf16, PRE-SWIZZLED A images ----------------
// Image layout (BM=256): img[(mb*8 + t)*32768 + swz(lrow, c8*16) + sub*8], so the
// GEMM's linear global_load_lds reproduces the swizzled 256-row A tile (m173).
__global__ __launch_bounds__(256) void k_norm_x(const float* __restrict__ x,
                                                unsigned char* __restrict__ img) {
    const int lane = threadIdx.x & 63;
    const int row  = blockIdx.x * 4 + (threadIdx.x >> 6);
    const float* xr = x + (size_t)row * DD;
    float4 v0 = *(const float4*)(xr + lane * 4);
    float4 v1 = *(const float4*)(xr + lane * 4 + 256);
    float s = v0.x*v0.x + v0.y*v0.y + v0.z*v0.z + v0.w*v0.w
            + v1.x*v1.x + v1.y*v1.y + v1.z*v1.z + v1.w*v1.w;
    #pragma unroll
    for (int m = 32; m; m >>= 1) s += __shfl_xor(s, m, 64);
    float rs = rsqrtf(fmaxf(s, 1e-12f));
    ushort4 o0, o1;
    o0.x = f2bf(v0.x * rs); o0.y = f2bf(v0.y * rs);
    o0.z = f2bf(v0.z * rs); o0.w = f2bf(v0.w * rs);
    o1.x = f2bf(v1.x * rs); o1.y = f2bf(v1.y * rs);
    o1.z = f2bf(v1.z * rs); o1.w = f2bf(v1.w * rs);

    const int mb   = row >> 8;            // which 256-row M block (0..1)
    const int lrow = row & 255;
    const int k0   = lane * 4;            // v0 covers k0..k0+3; v1 covers k0+256..
    const int t0   = k0 >> 6;             // 0..3 (v1 -> t0+4)
    const int c8   = (k0 >> 3) & 7;       // 16B chunk within 128B row
    const int sub  = (k0 >> 2) & 1;       // 8B half of the chunk
    const int base = (mb * 8 + t0) * 32768 + lrow * 128
                   + ((c8 * 16) ^ ((lrow & 7) << 4)) + sub * 8;
    *(ushort4*)(img + base)          = o0;
    *(ushort4*)(img + base + 131072) = o1;   // t0+4 image (4 * 32768)
}

// ---------------- K2: bf16 MFMA GEMM, 256x128 / 64x64 waves, R16 schedule ------
// R8 geometry x R16 technique: 8 waves of 64x64 (2048 FLOP per LDS-byte, -33%
// LDS traffic and -50% barriers per FLOP vs 64x32), open-scheduled KBODY,
// issue-early gll+loads, conflict-free 16B B staging, depth-3 B rotation,
// fused column norm + label fixup, sector-aligned NT epilogue.
// FIFO per iter: [B(t+2):16 riding][gll(t+1):4][B(t+3):16] -> WAITV(16) drains
// B(t+2)+gll, leaves B(t+3) riding the barrier. Max 36 in flight.
#define ABUF 32768
#define LDSZ (2 * ABUF + 2 * 16384 + 512 + 1024)   // 99840 -> 1 block/CU

__global__ __launch_bounds__(512, 2) void k_gemm(const unsigned char* __restrict__ img,
                                                 const float* __restrict__ W,
                                                 const int* __restrict__ lab,
                                                 float* __restrict__ out) {
    __shared__ __align__(16) unsigned char LDS[LDSZ];
    unsigned char* bufA = LDS;                  // 2 x 32KB
    unsigned char* bufB = LDS + 2 * ABUF;       // 2 x 16KB
    float* rn   = (float*)(LDS + 2 * ABUF + 32768);        // 512B
    int*   labs = (int*)(LDS + 2 * ABUF + 32768 + 512);    // 256 ints

    const int tid = threadIdx.x;
    const int bid = blockIdx.x;

    // bijective XCD swizzle (1564 = 8*195 + 4): mb-pairs of a W panel share one XCD L2
    const int xcd = bid & 7;
    const int jj  = bid >> 3;
    const int v   = (xcd < 4) ? (xcd * 196 + jj) : (784 + (xcd - 4) * 195 + jj);
    const int mb  = v & 1;
    const int nb  = v >> 1;
    const int M0 = mb * BM;
    const int N0 = nb * BN;

    const int lane = tid & 63;
    const int wid  = tid >> 6;     // 0..7
    const int wm = wid >> 1;       // 0..3 -> 64 rows each
    const int wn = wid & 1;        // 0..1 -> 64 cols each
    const int lr = lane & 15;
    const int lg = lane >> 4;

    // ---- fetch this block's 256 labels first ----
    if (tid < 256) labs[tid] = lab[M0 + tid];

    // ---- B staging tasks: 2 per thread; s = o*128 + n (o = k-octet 0..7) ----
    int b_go[2], b_ld[2];
    #pragma unroll
    for (int i = 0; i < 2; ++i) {
        int s  = tid + i * 512;
        int n  = s & 127;
        int o  = s >> 7;                       // k-octet
        int col = N0 + n;
        col = col < CC ? col : CC - 1;         // tail-panel clamp (dead cols)
        b_go[i] = o * 8 * CC + col;
        b_ld[i] = n * 128 + ((o * 16) ^ ((n & 7) << 4));   // conflict-free 16B slot
    }

    const unsigned char* imgA = img + mb * (8 * ABUF);
    const int lds_u = wid * 1024;              // wave-uniform part of linear offset

    float f0[2][8], f1[2][8], f2[2][8];        // B in flight, 3-deep rotation
    float bsq[2] = {0.f, 0.f};

#define WAITV_(N) asm volatile("s_waitcnt vmcnt(" #N ")" ::: "memory")
#define WAITV(N) WAITV_(N)
#define SB() __builtin_amdgcn_sched_barrier(0)

#define LOAD_B(FR, T) do {                                                     \
    _Pragma("unroll")                                                          \
    for (int i = 0; i < 2; ++i) {                                              \
        const float* p = W + b_go[i] + (size_t)(T) * (BK * CC);                \
        _Pragma("unroll")                                                      \
        for (int j = 0; j < 8; ++j)                                            \
            FR[i][j] = p[(size_t)j * CC];                                      \
    } } while (0)

// pack 8 f32 -> 4 u32 (cvt_pk) + ONE ds_write_b128 per task; fuse column sumsq
#define PACK_WRITE(FR, T) do {                                                 \
    unsigned char* dst = bufB + ((T) & 1) * 16384;                             \
    _Pragma("unroll")                                                          \
    for (int i = 0; i < 2; ++i) {                                              \
        _Pragma("unroll")                                                      \
        for (int j = 0; j < 8; ++j)                                            \
            bsq[i] += FR[i][j] * FR[i][j];                                     \
        uint4 w;                                                               \
        asm("v_cvt_pk_bf16_f32 %0, %1, %2" : "=v"(w.x) : "v"(FR[i][0]), "v"(FR[i][1])); \
        asm("v_cvt_pk_bf16_f32 %0, %1, %2" : "=v"(w.y) : "v"(FR[i][2]), "v"(FR[i][3])); \
        asm("v_cvt_pk_bf16_f32 %0, %1, %2" : "=v"(w.z) : "v"(FR[i][4]), "v"(FR[i][5])); \
        asm("v_cvt_pk_bf16_f32 %0, %1, %2" : "=v"(w.w) : "v"(FR[i][6]), "v"(FR[i][7])); \
        *(uint4*)(dst + b_ld[i]) = w;                                          \
    } } while (0)

#define GLL_A(T) do {                                                          \
    unsigned char* A_nxt = bufA + ((T) & 1) * ABUF;                            \
    const unsigned char* gsrc = imgA + (T) * ABUF;                             \
    _Pragma("unroll")                                                          \
    for (int i = 0; i < 4; ++i)                                                \
        gll16(gsrc + i * 8192 + lds_u + lane * 16, A_nxt + i * 8192 + lds_u);  \
    } while (0)

#define COMPUTE(T) do {                                                        \
    const unsigned char* A_cur = bufA + ((T) & 1) * ABUF;                      \
    const unsigned char* B_cur = bufB + ((T) & 1) * 16384;                     \
    __builtin_amdgcn_s_setprio(1);                                             \
    _Pragma("unroll")                                                          \
    for (int ks = 0; ks < 2; ++ks) {                                           \
        bf16x8 af[4], bfr[4];                                                  \
        _Pragma("unroll")                                                      \
        for (int mf = 0; mf < 4; ++mf)                                         \
            af[mf] = *(const bf16x8*)(A_cur + swz(wm * 64 + mf * 16 + lr, ks * 64 + lg * 16)); \
        _Pragma("unroll")                                                      \
        for (int nf = 0; nf < 4; ++nf)                                         \
            bfr[nf] = *(const bf16x8*)(B_cur + swz(wn * 64 + nf * 16 + lr, ks * 64 + lg * 16)); \
        _Pragma("unroll")                                                      \
        for (int mf = 0; mf < 4; ++mf)                                         \
            _Pragma("unroll")                                                  \
            for (int nf = 0; nf < 4; ++nf)                                     \
                acc[mf][nf] = __builtin_amdgcn_mfma_f32_16x16x32_bf16(         \
                    bfr[nf], af[mf], acc[mf][nf], 0, 0, 0);                    \
    }                                                                          \
    __builtin_amdgcn_s_setprio(0);                                             \
    } while (0)

// iter body: issue-early gll+loads; open region for COMPUTE+PACK interleave.
// FP = B(T+1) regs (packed now, loaded at T-2: retired, no wait), FN <- B(T+3).
#define KBODY(T, FP, FN) do {                                                  \
    if ((T) + 1 < KSTEPS) GLL_A((T) + 1);        /* gll BEFORE loads (FIFO) */ \
    if ((T) + 3 < KSTEPS) LOAD_B(FN, (T) + 3);                                 \
    COMPUTE(T);                                                                \
    if ((T) + 1 < KSTEPS) PACK_WRITE(FP, (T) + 1);                             \
    SB();                                                                      \
    if ((T) + 1 < KSTEPS) {                                                    \
        if ((T) + 3 < KSTEPS) { WAITV(16); } else { WAITV(0); }                \
        SB();                                                                  \
        asm volatile("s_waitcnt lgkmcnt(0)" ::: "memory"); SB();               \
        __builtin_amdgcn_s_barrier(); SB();                                    \
    } } while (0)

    f32x4 acc[4][4];
    #pragma unroll
    for (int mf = 0; mf < 4; ++mf)
        #pragma unroll
        for (int nf = 0; nf < 4; ++nf)
            acc[mf][nf] = (f32x4)0.f;

    // ---- prologue: B0:16, gll0:4, B1:16; pack B0 (auto vmcnt 20); B2:16;
    //      WAITV(32) drains gll0 only; B1+B2 ride through the barrier ----
    LOAD_B(f0, 0);
    GLL_A(0);
    LOAD_B(f1, 1);
    PACK_WRITE(f0, 0);                     // auto counted wait: drains B0 only
    LOAD_B(f2, 2);
    SB();
    WAITV(32); SB();                       // drain gll0 (+labs); B1:16 + B2:16 ride on
    asm volatile("s_waitcnt lgkmcnt(0)" ::: "memory"); SB();
    __builtin_amdgcn_s_barrier(); SB();

    KBODY(0, f1, f0);                      // pack B1, load B3->f0
    KBODY(1, f2, f1);                      // pack B2, load B4->f1
    KBODY(2, f0, f2);                      // pack B3, load B5->f2
    KBODY(3, f1, f0);                      // pack B4, load B6->f0
    KBODY(4, f2, f1);                      // pack B5, load B7->f1
    KBODY(5, f0, f2);                      // pack B6
    KBODY(6, f1, f0);                      // pack B7
    KBODY(7, f2, f1);                      // compute only

    // ---- deterministic column-norm reduction (reuse bufB) ----
    __syncthreads();
    float* part = (float*)bufB;                // [8][128] floats = 4KB
    #pragma unroll
    for (int i = 0; i < 2; ++i)
        part[tid + i * 512] = bsq[i];          // slot = o*128+n, unique owner
    __syncthreads();
    if (tid < BN) {
        float s = 0.f;
        #pragma unroll
        for (int o = 0; o < 8; ++o)
            s += part[o * BN + tid];           // fixed order -> deterministic
        rn[tid] = rsqrtf(fmaxf(s, 1e-12f));
    }
    __syncthreads();                           // part[] dead after this point

    // ---- epilogue: 64-row staging (4 phases) -> per-row fixup -> NT stores ----
    float* stag = (float*)LDS;                 // 64 rows x 132 floats = 33792B
    #pragma unroll
    for (int rd = 0; rd < 4; ++rd) {
        if (wm == rd) {                        // 2 waves stage their 64x128 tile
            #pragma unroll
            for (int mf = 0; mf < 4; ++mf) {
                const int ml = mf * 16 + lr;
                #pragma unroll
                for (int nf = 0; nf < 4; ++nf) {
                    const int nl = wn * 64 + nf * 16 + lg * 4;
                    const f32x4 rn4 = *(const f32x4*)(rn + nl);
                    f32x4 o;
                    #pragma unroll
                    for (int r = 0; r < 4; ++r)
                        o[r] = acc[mf][nf][r] * rn4[r];
                    *(f32x4*)(stag + ml * 132 + nl) = o;
                }
            }
        }
        __syncthreads();
        // fused margin fixup: one thread per staged row (64 rows), rare branch
        if (tid < 64) {
            const int c   = labs[rd * 64 + tid];   // this row's label column
            const int off = c - N0;
            if (off >= 0 && off < BN) {
                float val = stag[tid * 132 + off];
                val = fminf(fmaxf(val, -1.f), 1.f);
                float th = fminf(acosf(val) + MARGIN2, PI_F);
                stag[tid * 132 + off] = cosf(th);  // M3 == 0
            }
        }
        __syncthreads();
        // 64 rows x 32 float4 = 2048 slots; 512 threads x 4 iters
        #pragma unroll
        for (int j = tid; j < 2048; j += 512) {
            const int m = j >> 5;
            const int n = (j & 31) * 4;
            if (N0 + n + 4 <= CC) {
                f32x4 o = *(const f32x4*)(stag + m * 132 + n);
                __builtin_nontemporal_store(o,
                    (f32x4*)(out + (size_t)(M0 + rd * 64 + m) * CC + N0 + n));
            }
        }
        __syncthreads();
    }
}

extern "C" void kernel_launch(void* const* d_in, const int* in_sizes, int n_in,
                              void* d_out, int out_size, void* d_ws, size_t ws_size,
                              hipStream_t stream) {
    const float* x   = (const float*)d_in[0];
    const float* W   = (const float*)d_in[1];
    const int*   lab = (const int*)d_in[2];
    float* out = (float*)d_out;

    unsigned char* img = (unsigned char*)d_ws;   // 512KB pre-swizzled xn images

    k_norm_x<<<dim3(BB / 4), dim3(256), 0, stream>>>(x, img);
    k_gemm<<<dim3(GRID), dim3(512), 0, stream>>>(img, W, lab, out);
}

// Round 21
// 102.600 us; speedup vs baseline: 1.1143x; 1.1143x over previous
//
#include <hip/hip_runtime.h>
#include <math.h>

#define BB 512       // batch rows (M)
#define DD 512       // depth (K)
#define CC 100000    // classes (N)
#define MARGIN2 0.5f
#define PI_F 3.14159265358979323846f

#define BM 128
#define BN 128
#define BK 64
#define KSTEPS (DD / BK)     // 8
#define NPAN 782             // ceil(100000/128), last panel 32 cols
#define GRID (4 * NPAN)      // 3128 = 8 * 391 exactly

typedef __bf16 bf16x8 __attribute__((ext_vector_type(8)));
typedef float f32x4 __attribute__((ext_vector_type(4)));

static __device__ __forceinline__ unsigned short f2bf(float f) {
    union { float f; unsigned u; } v; v.f = f;
    unsigned r = v.u + 0x7FFFu + ((v.u >> 16) & 1u);   // round-to-nearest-even
    return (unsigned short)(r >> 16);
}

// swizzled LDS byte offset for row-major [row][64 x bf16] tiles (row stride 128B)
static __device__ __forceinline__ int swz(int row, int kbyte) {
    return row * 128 + (kbyte ^ ((row & 7) << 4));
}

// async global->LDS, 16B per lane; LDS dest = wave-uniform base + lane*16 (HW rule)
static __device__ __forceinline__ void gll16(const unsigned char* g, unsigned char* l) {
    __builtin_amdgcn_global_load_lds(
        (const __attribute__((address_space(1))) void*)g,
        (__attribute__((address_space(3))) void*)l, 16, 0, 0);
}

// ---------------- K1: row-normalize x -> bf16, PRE-SWIZZLED A images ----------------
// Image layout for BM=128: img[(mb*8 + t)*16384 + swz(lrow, c8*16) + sub*8],
// mb = row>>7, lrow = row&127 -> gemm's linear global_load_lds reproduces the
// swizzled Ash layout exactly (m173 pattern).
__global__ __launch_bounds__(256) void k_norm_x(const float* __restrict__ x,
                                                unsigned char* __restrict__ img) {
    const int lane = threadIdx.x & 63;
    const int row  = blockIdx.x * 4 + (threadIdx.x >> 6);
    const float* xr = x + (size_t)row * DD;
    float4 v0 = *(const float4*)(xr + lane * 4);
    float4 v1 = *(const float4*)(xr + lane * 4 + 256);
    float s = v0.x*v0.x + v0.y*v0.y + v0.z*v0.z + v0.w*v0.w
            + v1.x*v1.x + v1.y*v1.y + v1.z*v1.z + v1.w*v1.w;
    #pragma unroll
    for (int m = 32; m; m >>= 1) s += __shfl_xor(s, m, 64);
    float rs = rsqrtf(fmaxf(s, 1e-12f));
    ushort4 o0, o1;
    o0.x = f2bf(v0.x * rs); o0.y = f2bf(v0.y * rs);
    o0.z = f2bf(v0.z * rs); o0.w = f2bf(v0.w * rs);
    o1.x = f2bf(v1.x * rs); o1.y = f2bf(v1.y * rs);
    o1.z = f2bf(v1.z * rs); o1.w = f2bf(v1.w * rs);

    const int mb   = row >> 7;            // which 128-row M block (0..3)
    const int lrow = row & 127;
    const int k0   = lane * 4;            // v0 covers k0..k0+3; v1 covers k0+256..
    const int t0   = k0 >> 6;             // 0..3 (v1 -> t0+4)
    const int c8   = (k0 >> 3) & 7;       // 16B chunk within 128B row
    const int sub  = (k0 >> 2) & 1;       // 8B half of the chunk
    const int base = (mb * 8 + t0) * 16384 + lrow * 128
                   + ((c8 * 16) ^ ((lrow & 7) << 4)) + sub * 8;
    *(ushort4*)(img + base)         = o0;
    *(ushort4*)(img + base + 65536) = o1;    // t0+4 image (4 * 16384)
}

// ---------------- K2: bf16 MFMA GEMM + fused margin fixup (R17 core) -----------
// Open-scheduled pipeline: conflict-free 16B B staging, depth-3 B rotation,
// gll-A from pre-swizzled image, issue-early loads, XCD swizzle, fused column
// norm, fused label fixup. Epilogue stages 64 rows/phase (2 phases, 6 barriers)
// - the whole 65.5KB K-loop LDS is dead post-loop, so the staging is free.
#define ABUF 16384
#define LDSZ (2 * ABUF + 2 * 16384 + 512 + 512)   // 66560 -> 2 blocks/CU

__global__ __launch_bounds__(512, 4) void k_gemm(const unsigned char* __restrict__ img,
                                                 const float* __restrict__ W,
                                                 const int* __restrict__ lab,
                                                 float* __restrict__ out) {
    __shared__ __align__(16) unsigned char LDS[LDSZ];
    unsigned char* bufA = LDS;                  // 2 x 16KB
    unsigned char* bufB = LDS + 2 * ABUF;       // 2 x 16KB
    float* rn  = (float*)(LDS + 2 * ABUF + 32768);        // 512B
    int*   labs = (int*)(LDS + 2 * ABUF + 32768 + 512);   // 128 ints

    const int tid = threadIdx.x;
    const int bid = blockIdx.x;

    // bijective XCD swizzle: 3128 = 8*391; 4 mb-sharers of a W panel -> same XCD L2
    const int v  = (bid & 7) * 391 + (bid >> 3);
    const int mb = v & 3;
    const int nb = v >> 2;
    const int M0 = mb * BM;
    const int N0 = nb * BN;

    const int lane = tid & 63;
    const int wid  = tid >> 6;     // 0..7
    const int wm = wid >> 2;       // 0..1 -> 64 rows each
    const int wn = wid & 3;        // 0..3 -> 32 cols each
    const int lr = lane & 15;
    const int lg = lane >> 4;

    // ---- fetch this block's 128 labels first (waves 0-1) ----
    if (tid < 128) labs[tid] = lab[M0 + tid];

    // ---- B staging tasks: 2 per thread; s = o*128 + n (o = k-octet 0..7) ----
    int b_go[2], b_ld[2];
    #pragma unroll
    for (int i = 0; i < 2; ++i) {
        int s  = tid + i * 512;
        int n  = s & 127;
        int o  = s >> 7;                       // k-octet
        int col = N0 + n;
        col = col < CC ? col : CC - 1;         // tail-panel clamp (dead cols)
        b_go[i] = o * 8 * CC + col;
        b_ld[i] = n * 128 + ((o * 16) ^ ((n & 7) << 4));   // conflict-free 16B slot
    }

    const unsigned char* imgA = img + mb * (8 * ABUF);
    const int lds_u = wid * 2048;              // wave-uniform part of linear offset

    float f0[2][8], f1[2][8], f2[2][8];        // B in flight, 3-deep rotation
    float bsq[2] = {0.f, 0.f};

#define WAITV_(N) asm volatile("s_waitcnt vmcnt(" #N ")" ::: "memory")
#define WAITV(N) WAITV_(N)
#define SB() __builtin_amdgcn_sched_barrier(0)

#define LOAD_B(FR, T) do {                                                     \
    _Pragma("unroll")                                                          \
    for (int i = 0; i < 2; ++i) {                                              \
        const float* p = W + b_go[i] + (size_t)(T) * (BK * CC);                \
        _Pragma("unroll")                                                      \
        for (int j = 0; j < 8; ++j)                                            \
            FR[i][j] = p[(size_t)j * CC];                                      \
    } } while (0)

// pack 8 f32 -> 4 u32 (cvt_pk) + ONE ds_write_b128 per task; fuse column sumsq
#define PACK_WRITE(FR, T) do {                                                 \
    unsigned char* dst = bufB + ((T) & 1) * 16384;                             \
    _Pragma("unroll")                                                          \
    for (int i = 0; i < 2; ++i) {                                              \
        _Pragma("unroll")                                                      \
        for (int j = 0; j < 8; ++j)                                            \
            bsq[i] += FR[i][j] * FR[i][j];                                     \
        uint4 w;                                                               \
        asm("v_cvt_pk_bf16_f32 %0, %1, %2" : "=v"(w.x) : "v"(FR[i][0]), "v"(FR[i][1])); \
        asm("v_cvt_pk_bf16_f32 %0, %1, %2" : "=v"(w.y) : "v"(FR[i][2]), "v"(FR[i][3])); \
        asm("v_cvt_pk_bf16_f32 %0, %1, %2" : "=v"(w.z) : "v"(FR[i][4]), "v"(FR[i][5])); \
        asm("v_cvt_pk_bf16_f32 %0, %1, %2" : "=v"(w.w) : "v"(FR[i][6]), "v"(FR[i][7])); \
        *(uint4*)(dst + b_ld[i]) = w;                                          \
    } } while (0)

#define GLL_A(T) do {                                                          \
    unsigned char* A_nxt = bufA + ((T) & 1) * ABUF;                            \
    const unsigned char* gsrc = imgA + (T) * ABUF;                             \
    gll16(gsrc + lds_u + lane * 16, A_nxt + lds_u);                            \
    gll16(gsrc + lds_u + 1024 + lane * 16, A_nxt + lds_u + 1024);              \
    } while (0)

#define COMPUTE(T) do {                                                        \
    const unsigned char* A_cur = bufA + ((T) & 1) * ABUF;                      \
    const unsigned char* B_cur = bufB + ((T) & 1) * 16384;                     \
    __builtin_amdgcn_s_setprio(1);                                             \
    _Pragma("unroll")                                                          \
    for (int ks = 0; ks < 2; ++ks) {                                           \
        bf16x8 af[4], bfr[2];                                                  \
        _Pragma("unroll")                                                      \
        for (int mf = 0; mf < 4; ++mf)                                         \
            af[mf] = *(const bf16x8*)(A_cur + swz(wm * 64 + mf * 16 + lr, ks * 64 + lg * 16)); \
        _Pragma("unroll")                                                      \
        for (int nf = 0; nf < 2; ++nf)                                         \
            bfr[nf] = *(const bf16x8*)(B_cur + swz(wn * 32 + nf * 16 + lr, ks * 64 + lg * 16)); \
        _Pragma("unroll")                                                      \
        for (int mf = 0; mf < 4; ++mf)                                         \
            _Pragma("unroll")                                                  \
            for (int nf = 0; nf < 2; ++nf)                                     \
                acc[mf][nf] = __builtin_amdgcn_mfma_f32_16x16x32_bf16(         \
                    bfr[nf], af[mf], acc[mf][nf], 0, 0, 0);                    \
    }                                                                          \
    __builtin_amdgcn_s_setprio(0);                                             \
    } while (0)

// iter body: issue-early gll+loads; open region for COMPUTE+PACK interleave.
// FP = B(T+1) regs (packed now, loaded at T-2: retired, no wait), FN <- B(T+3).
#define KBODY(T, FP, FN) do {                                                  \
    if ((T) + 1 < KSTEPS) GLL_A((T) + 1);        /* gll BEFORE loads (FIFO) */ \
    if ((T) + 3 < KSTEPS) LOAD_B(FN, (T) + 3);                                 \
    COMPUTE(T);                                                                \
    if ((T) + 1 < KSTEPS) PACK_WRITE(FP, (T) + 1);                             \
    SB();                                                                      \
    if ((T) + 1 < KSTEPS) {                                                    \
        if ((T) + 3 < KSTEPS) { WAITV(16); } else { WAITV(0); }                \
        SB();                                                                  \
        asm volatile("s_waitcnt lgkmcnt(0)" ::: "memory"); SB();               \
        __builtin_amdgcn_s_barrier(); SB();                                    \
    } } while (0)

    f32x4 acc[4][2];
    #pragma unroll
    for (int mf = 0; mf < 4; ++mf)
        #pragma unroll
        for (int nf = 0; nf < 2; ++nf)
            acc[mf][nf] = (f32x4)0.f;

    // ---- prologue: B0, gll0, B1; pack B0 (auto counted); B2; drain gll (32) ----
    LOAD_B(f0, 0);
    GLL_A(0);
    LOAD_B(f1, 1);
    PACK_WRITE(f0, 0);                     // auto counted wait: drains B0 only
    LOAD_B(f2, 2);
    SB();
    WAITV(32); SB();                       // drain gll0 (+lab); B1:16 + B2:16 ride on
    asm volatile("s_waitcnt lgkmcnt(0)" ::: "memory"); SB();
    __builtin_amdgcn_s_barrier(); SB();

    KBODY(0, f1, f0);                      // pack B1, load B3->f0
    KBODY(1, f2, f1);                      // pack B2, load B4->f1
    KBODY(2, f0, f2);                      // pack B3, load B5->f2
    KBODY(3, f1, f0);                      // pack B4, load B6->f0
    KBODY(4, f2, f1);                      // pack B5, load B7->f1
    KBODY(5, f0, f2);                      // pack B6
    KBODY(6, f1, f0);                      // pack B7
    KBODY(7, f2, f1);                      // compute only

    // ---- deterministic column-norm reduction (reuse bufB) ----
    __syncthreads();
    float* part = (float*)bufB;                // [8][128] floats = 4KB
    #pragma unroll
    for (int i = 0; i < 2; ++i)
        part[tid + i * 512] = bsq[i];          // slot = o*128+n, unique owner
    __syncthreads();
    if (tid < BN) {
        float s = 0.f;
        #pragma unroll
        for (int o = 0; o < 8; ++o)
            s += part[o * BN + tid];           // fixed order -> deterministic
        rn[tid] = rsqrtf(fmaxf(s, 1e-12f));
    }
    __syncthreads();                           // part[] dead after this point

    // ---- epilogue: 64-row staging (2 phases) -> per-row fixup -> NT stores ----
    // stag = 64 rows x 132 floats = 33792B over bufA+bufB head (both dead).
    float* stag = (float*)LDS;
    #pragma unroll
    for (int rd = 0; rd < 2; ++rd) {
        if (wm == rd) {                        // 4 waves stage their 64x128 tile
            #pragma unroll
            for (int mf = 0; mf < 4; ++mf) {
                const int ml = mf * 16 + lr;
                #pragma unroll
                for (int nf = 0; nf < 2; ++nf) {
                    const int nl = wn * 32 + nf * 16 + lg * 4;
                    const f32x4 rn4 = *(const f32x4*)(rn + nl);
                    f32x4 o;
                    #pragma unroll
                    for (int r = 0; r < 4; ++r)
                        o[r] = acc[mf][nf][r] * rn4[r];
                    *(f32x4*)(stag + ml * 132 + nl) = o;
                }
            }
        }
        __syncthreads();
        // fused margin fixup: one thread per staged row (64 rows), rare branch
        if (tid < 64) {
            const int c   = labs[rd * 64 + tid];   // this row's label column
            const int off = c - N0;
            if (off >= 0 && off < BN) {
                float val = stag[tid * 132 + off];
                val = fminf(fmaxf(val, -1.f), 1.f);
                float th = fminf(acosf(val) + MARGIN2, PI_F);
                stag[tid * 132 + off] = cosf(th);  // M3 == 0
            }
        }
        __syncthreads();
        // 64 rows x 32 float4 = 2048 slots; 512 threads x 4 iters
        #pragma unroll
        for (int j = tid; j < 2048; j += 512) {
            const int m = j >> 5;
            const int n = (j & 31) * 4;
            if (N0 + n + 4 <= CC) {
                f32x4 o = *(const f32x4*)(stag + m * 132 + n);
                __builtin_nontemporal_store(o,
                    (f32x4*)(out + (size_t)(M0 + rd * 64 + m) * CC + N0 + n));
            }
        }
        __syncthreads();
    }
}

extern "C" void kernel_launch(void* const* d_in, const int* in_sizes, int n_in,
                              void* d_out, int out_size, void* d_ws, size_t ws_size,
                              hipStream_t stream) {
    const float* x   = (const float*)d_in[0];
    const float* W   = (const float*)d_in[1];
    const int*   lab = (const int*)d_in[2];
    float* out = (float*)d_out;

    unsigned char* img = (unsigned char*)d_ws;   // 512KB pre-swizzled xn images

    k_norm_x<<<dim3(BB / 4), dim3(256), 0, stream>>>(x, img);
    k_gemm<<<dim3(GRID), dim3(512), 0, stream>>>(img, W, lab, out);
}